// Round 11
// baseline (196.049 us; speedup 1.0000x reference)
//
#include <hip/hip_runtime.h>
#include <hip/hip_bf16.h>

typedef __bf16 bf16;
typedef __bf16 bf16x4 __attribute__((ext_vector_type(4)));
typedef __bf16 bf16x8 __attribute__((ext_vector_type(8)));
typedef float  f32x4  __attribute__((ext_vector_type(4)));
typedef float  f32x16 __attribute__((ext_vector_type(16)));
typedef unsigned int uint32x2 __attribute__((ext_vector_type(2)));

#define DEVI static __device__ __forceinline__

constexpr float SCALE2  = 0.063758716f;           // log2(e)/sqrt(512)
constexpr float L2MU    = -9.9999852f;            // log2(1/1024 + 1e-8)
constexpr int   LDT     = 72;                     // padded LDS row stride (bf16 elems)

DEVI f32x4 mfma16(bf16x8 a, bf16x8 b, f32x4 c) {
    return __builtin_amdgcn_mfma_f32_16x16x32_bf16(a, b, c, 0, 0, 0);
}
DEVI f32x16 mfma32(bf16x8 a, bf16x8 b, f32x16 c) {
    return __builtin_amdgcn_mfma_f32_32x32x16_bf16(a, b, c, 0, 0, 0);
}
// packed f32->bf16 pair (no builtin on gfx950; m240)
DEVI unsigned cvtpk(float lo, float hi) {
    unsigned r;
    asm("v_cvt_pk_bf16_f32 %0, %1, %2" : "=v"(r) : "v"(lo), "v"(hi));
    return r;
}

// load 8 fp32, convert to bf16x8
DEVI bf16x8 cvt8(const float* __restrict__ p) {
    const float4 f0 = *(const float4*)p;
    const float4 f1 = *(const float4*)(p + 4);
    bf16x8 h;
    h[0] = (bf16)f0.x; h[1] = (bf16)f0.y; h[2] = (bf16)f0.z; h[3] = (bf16)f0.w;
    h[4] = (bf16)f1.x; h[5] = (bf16)f1.y; h[6] = (bf16)f1.z; h[7] = (bf16)f1.w;
    return h;
}

// ---------------------------------------------------------------------------
// one-shot fp32 -> bf16 weight conversion (512x512), grid 128 x 256
// ---------------------------------------------------------------------------
__global__ __launch_bounds__(256)
void cvtw_kernel(const float* __restrict__ W, bf16* __restrict__ Wb)
{
    const int i = (blockIdx.x * 256 + threadIdx.x) * 8;
    *(bf16x8*)(&Wb[i]) = cvt8(W + i);
}

// ---------------------------------------------------------------------------
// GEMM: C[row][col] = sum_k A[row][k]*Bb[col][k] + bias[col]   (Bb bf16)
// EPI==0: A fp32 (=Q). scatter bf16 to head-major Qh [64][1024][64] and
//         transposed QhT [64][64][1024] (b64 packed stores).
// EPI==1: A bf16 (=X0). T[row][col] = X0[row][col] + relu(C)  (fp32 out)
// M=8192, N=512, K=512. Tile 64x64, BK=64, 4 waves (2x2 of 32x32).
// XCD swizzle; DOUBLE-BUFFERED register-prefetch staging (1 barrier/K-step).
// (round-5/9 harness-proven version)
// ---------------------------------------------------------------------------
template<int EPI>
__global__ __launch_bounds__(256)
void gemm_kernel(const void* __restrict__ Ap, const bf16* __restrict__ Bb,
                 const float* __restrict__ bias, const bf16* __restrict__ X0,
                 bf16* __restrict__ outQh, bf16* __restrict__ outQhT,
                 float* __restrict__ outT)
{
    __shared__ bf16 sA[2][64 * LDT];
    __shared__ bf16 sB[2][64 * LDT];
    const int tid = threadIdx.x;
    const int lin = blockIdx.y * 8 + blockIdx.x;        // grid (8,128) = 1024
    const int wk  = ((lin & 7) << 7) | (lin >> 3);      // 128 blocks/XCD chunk
    const int rowBase = (wk >> 3) * 64;
    const int colBase = (wk & 7) * 64;
    const int w = tid >> 6, lane = tid & 63, quad = lane >> 4, l16 = lane & 15;
    const int wr = (w >> 1) * 32, wc = (w & 1) * 32;
    const int r0 = tid >> 3, kb0 = tid & 7;             // staging coords (2 rows/thread)

    f32x4 acc[2][2];
    #pragma unroll
    for (int i = 0; i < 2; ++i)
        #pragma unroll
        for (int j = 0; j < 2; ++j)
            #pragma unroll
            for (int e = 0; e < 4; ++e) acc[i][j][e] = 0.f;

    // stage kt=0 into buffer 0
    #pragma unroll
    for (int it = 0; it < 2; ++it) {
        const int r = it * 32 + r0;
        if (EPI == 0)
            *(bf16x8*)(&sA[0][r * LDT + kb0 * 8]) =
                cvt8((const float*)Ap + (size_t)(rowBase + r) * 512 + kb0 * 8);
        else
            *(uint4*)(&sA[0][r * LDT + kb0 * 8]) =
                *(const uint4*)((const bf16*)Ap + (size_t)(rowBase + r) * 512 + kb0 * 8);
        *(uint4*)(&sB[0][r * LDT + kb0 * 8]) =
            *(const uint4*)(Bb + (size_t)(colBase + r) * 512 + kb0 * 8);
    }
    __syncthreads();

    for (int kt8 = 0; kt8 < 8; ++kt8) {
        const int cur = kt8 & 1;
        float4 pfa[2][2];
        uint4  pfa16[2], pfb[2];
        if (kt8 < 7) {
            const int kn = (kt8 + 1) * 64;
            #pragma unroll
            for (int it = 0; it < 2; ++it) {
                const int r = it * 32 + r0;
                if (EPI == 0) {
                    const float* ap = (const float*)Ap + (size_t)(rowBase + r) * 512 + kn + kb0 * 8;
                    pfa[it][0] = *(const float4*)ap;
                    pfa[it][1] = *(const float4*)(ap + 4);
                } else {
                    pfa16[it] = *(const uint4*)((const bf16*)Ap + (size_t)(rowBase + r) * 512 + kn + kb0 * 8);
                }
                pfb[it] = *(const uint4*)(Bb + (size_t)(colBase + r) * 512 + kn + kb0 * 8);
            }
        }

        #pragma unroll
        for (int kk = 0; kk < 2; ++kk) {
            bf16x8 a[2], b[2];
            #pragma unroll
            for (int i = 0; i < 2; ++i)
                a[i] = *(const bf16x8*)(&sA[cur][(wr + i * 16 + l16) * LDT + kk * 32 + quad * 8]);
            #pragma unroll
            for (int j = 0; j < 2; ++j)
                b[j] = *(const bf16x8*)(&sB[cur][(wc + j * 16 + l16) * LDT + kk * 32 + quad * 8]);
            #pragma unroll
            for (int i = 0; i < 2; ++i)
                #pragma unroll
                for (int j = 0; j < 2; ++j)
                    acc[i][j] = mfma16(a[i], b[j], acc[i][j]);
        }

        if (kt8 < 7) {
            #pragma unroll
            for (int it = 0; it < 2; ++it) {
                const int r = it * 32 + r0;
                if (EPI == 0) {
                    bf16x8 h;
                    h[0] = (bf16)pfa[it][0].x; h[1] = (bf16)pfa[it][0].y;
                    h[2] = (bf16)pfa[it][0].z; h[3] = (bf16)pfa[it][0].w;
                    h[4] = (bf16)pfa[it][1].x; h[5] = (bf16)pfa[it][1].y;
                    h[6] = (bf16)pfa[it][1].z; h[7] = (bf16)pfa[it][1].w;
                    *(bf16x8*)(&sA[cur ^ 1][r * LDT + kb0 * 8]) = h;
                } else {
                    *(uint4*)(&sA[cur ^ 1][r * LDT + kb0 * 8]) = pfa16[it];
                }
                *(uint4*)(&sB[cur ^ 1][r * LDT + kb0 * 8]) = pfb[it];
            }
        }
        __syncthreads();
    }

    #pragma unroll
    for (int i = 0; i < 2; ++i) {
        #pragma unroll
        for (int j = 0; j < 2; ++j) {
            const int col = colBase + wc + j * 16 + l16;
            const float bv = bias[col];
            if (EPI == 0) {
                const int hh = col >> 6, jj = col & 63;
                const int rowA = rowBase + wr + i * 16 + quad * 4;
                const int bb = rowA >> 10, iib = rowA & 1023;
                const int bhh = (hh << 3) + bb;
                bf16x4 pk;
                #pragma unroll
                for (int rg = 0; rg < 4; ++rg) {
                    const float z = acc[i][j][rg] + bv;
                    pk[rg] = (bf16)z;
                    outQh[((size_t)(bhh * 1024 + iib + rg) << 6) + jj] = (bf16)z;
                }
                if (outQhT)
                    *(bf16x4*)(&outQhT[(((size_t)bhh * 64 + jj) << 10) + iib]) = pk;
            } else {
                #pragma unroll
                for (int rg = 0; rg < 4; ++rg) {
                    const int row = rowBase + wr + i * 16 + quad * 4 + rg;
                    const float z = acc[i][j][rg] + bv;
                    const float x0 = (float)X0[(size_t)row * 512 + col];
                    outT[(size_t)row * 512 + col] = x0 + fmaxf(z, 0.f);
                }
            }
        }
    }
}

// ---------------------------------------------------------------------------
// Sinkhorn LSE passes over S = Q_ Q_^T / sqrt(512)  (S symmetric), log2-domain:
// ADD_U==0: out[i] = L2MU - log2(sum_m 2^(S[i][m]*s2))             (= u2)
// ADD_U==1: out[m] = L2MU - log2(sum_i 2^(S[m][i]*s2 + u2[i]))     (= v2)
// 64 rows/block, 4 waves x 16 rows; grid (16, 64) = 1024 blocks = 4/CU.
// Qi A-frags are mt-invariant -> hoisted to registers (no sQi LDS).
// (round-4/5/9 harness-proven version)
// ---------------------------------------------------------------------------
template<int ADD_U>
__global__ __launch_bounds__(256, 4)
void sink_lse_kernel(const bf16* __restrict__ Qh, const float* __restrict__ uin,
                     float* __restrict__ out)
{
    __shared__ bf16 sQm[2][64 * LDT];       // 18432 B
    __shared__ float su[1024];              //  4096 B
    const int tid = threadIdx.x;
    const int lin = blockIdx.y * 16 + blockIdx.x;
    const int wk  = ((lin & 7) << 7) | (lin >> 3);
    const int bh = wk >> 4;
    const int rowTile = (wk & 15) * 64;
    const bf16* Qb = Qh + ((size_t)bh << 16);   // bh*1024*64

    if (ADD_U)
        *(float4*)(&su[tid * 4]) = *(const float4*)(uin + (bh << 10) + tid * 4);

    const int r0 = tid >> 3, kb0 = tid & 7;
    #pragma unroll
    for (int it = 0; it < 2; ++it)
        *(uint4*)(&sQm[0][(it * 32 + r0) * LDT + kb0 * 8]) =
            *(const uint4*)(Qb + ((it * 32 + r0) << 6) + kb0 * 8);

    const int w = tid >> 6, lane = tid & 63, quad = lane >> 4, l16 = lane & 15;
    bf16x8 afr[2];
    #pragma unroll
    for (int kk = 0; kk < 2; ++kk)
        afr[kk] = *(const bf16x8*)(Qb + ((rowTile + w * 16 + l16) << 6) + kk * 32 + quad * 8);
    __syncthreads();

    float rsum[4] = {0.f, 0.f, 0.f, 0.f};

    for (int mt = 0; mt < 16; ++mt) {
        const int cur = mt & 1;
        uint4 pf[2];
        if (mt < 15) {
            #pragma unroll
            for (int it = 0; it < 2; ++it)
                pf[it] = *(const uint4*)(Qb + (((mt + 1) * 64 + it * 32 + r0) << 6) + kb0 * 8);
        }

        f32x4 acc[4];
        #pragma unroll
        for (int ct = 0; ct < 4; ++ct)
            #pragma unroll
            for (int e = 0; e < 4; ++e) acc[ct][e] = 0.f;

        #pragma unroll
        for (int kk = 0; kk < 2; ++kk) {
            bf16x8 bfr[4];
            #pragma unroll
            for (int ct = 0; ct < 4; ++ct)
                bfr[ct] = *(const bf16x8*)(&sQm[cur][(ct * 16 + l16) * LDT + kk * 32 + quad * 8]);
            #pragma unroll
            for (int ct = 0; ct < 4; ++ct)
                acc[ct] = mfma16(afr[kk], bfr[ct], acc[ct]);
        }
        #pragma unroll
        for (int ct = 0; ct < 4; ++ct) {
            const float uadd = ADD_U ? su[mt * 64 + ct * 16 + l16] : 0.f;
            #pragma unroll
            for (int rg = 0; rg < 4; ++rg)
                rsum[rg] += __builtin_amdgcn_exp2f(fmaf(acc[ct][rg], SCALE2, uadd));
        }

        if (mt < 15) {
            #pragma unroll
            for (int it = 0; it < 2; ++it)
                *(uint4*)(&sQm[cur ^ 1][(it * 32 + r0) * LDT + kb0 * 8]) = pf[it];
        }
        __syncthreads();
    }
    #pragma unroll
    for (int off = 1; off < 16; off <<= 1)
        #pragma unroll
        for (int rg = 0; rg < 4; ++rg)
            rsum[rg] += __shfl_xor(rsum[rg], off);

    if (l16 == 0) {
        #pragma unroll
        for (int rg = 0; rg < 4; ++rg)
            out[(bh << 10) + rowTile + w * 16 + quad * 4 + rg] =
                L2MU - __builtin_amdgcn_logf(rsum[rg]);
    }
}

// ---------------------------------------------------------------------------
// O_ = Q_ + A Q_,  A[i][m] = 2^(S[i][m]*s2 + u2[i] + v2[m] + 10).
// Swapped 32x32x16 QK^T; PV A-frags in-register (cvt_pk + permlane32_swap).
// 128 rows/block, 4 waves x 32 rows; grid (8, 64), XCD-swizzled.
// Round-9 harness-proven version (194.4 us): sQi PADDED, sv in LDS,
// bq hoisted, __launch_bounds__(256,2). NO-TOUCH list: unpadded sQi /
// global-vf (R8+R10 corrupt, absmax 8.016) and (256,3) cap (R7 corrupt).
// ---------------------------------------------------------------------------
template<int USE_T>
__global__ __launch_bounds__(256, 2)
void sink_av_kernel(const bf16* __restrict__ Qh, const bf16* __restrict__ QhT,
                    const float* __restrict__ u, const float* __restrict__ v,
                    float* __restrict__ O)
{
    __shared__ bf16 sQi[128 * LDT];         // 18432 B
    __shared__ bf16 sQm[2][64 * LDT];       // 18432 B
    __shared__ bf16 sQmT[2][64 * LDT];      // 18432 B  [dcol][m]
    __shared__ float sv[1024];              //  4096 B   -> total 59392 B
    const int tid = threadIdx.x;
    const int lin = blockIdx.y * 8 + blockIdx.x;
    const int wk  = ((lin & 7) << 6) | (lin >> 3);
    const int bh = wk >> 3;
    const int rowTile = (wk & 7) * 128;
    const bf16* Qb = Qh + ((size_t)bh << 16);
    const bf16* QbT = QhT + ((size_t)bh << 16);
    const int w = tid >> 6, lane = tid & 63, hi = lane >> 5, l31 = lane & 31;
    const int r0 = tid >> 3, kb0 = tid & 7;

    #pragma unroll
    for (int it = 0; it < 4; ++it) {
        int idx = it * 256 + tid;
        int r = idx >> 3, kb = idx & 7;
        *(uint4*)(&sQi[r * LDT + kb * 8]) =
            *(const uint4*)(Qb + ((rowTile + r) << 6) + kb * 8);
    }
    *(float4*)(&sv[tid * 4]) = *(const float4*)(v + (bh << 10) + tid * 4);
    const float u2p = u[(bh << 10) + rowTile + w * 32 + l31] + 10.f;

    #pragma unroll
    for (int it = 0; it < 2; ++it) {
        const int r = it * 32 + r0;
        uint4 val = *(const uint4*)(Qb + (r << 6) + kb0 * 8);
        *(uint4*)(&sQm[0][r * LDT + kb0 * 8]) = val;
        if (USE_T) {
            *(uint4*)(&sQmT[0][r * LDT + kb0 * 8]) =
                *(const uint4*)(QbT + (r << 10) + kb0 * 8);
        } else {
            union { uint4 q; bf16 e[8]; } cv; cv.q = val;
            #pragma unroll
            for (int j = 0; j < 8; ++j)
                sQmT[0][(kb0 * 8 + j) * LDT + r] = cv.e[j];
        }
    }
    __syncthreads();

    // hoist the mt-invariant Qi B-frags (row w*32 + l31) to registers
    bf16x8 bq[4];
    #pragma unroll
    for (int ks = 0; ks < 4; ++ks)
        bq[ks] = *(const bf16x8*)(&sQi[(w * 32 + l31) * LDT + ks * 16 + hi * 8]);

    f32x16 accO[2];
    #pragma unroll
    for (int dt = 0; dt < 2; ++dt)
        #pragma unroll
        for (int e = 0; e < 16; ++e) accO[dt][e] = 0.f;

    for (int mt = 0; mt < 16; ++mt) {
        const int cur = mt & 1;
        uint4 pfm[2], pft[2];
        if (mt < 15) {
            #pragma unroll
            for (int it = 0; it < 2; ++it) {
                const int r = it * 32 + r0;
                pfm[it] = *(const uint4*)(Qb + (((mt + 1) * 64 + r) << 6) + kb0 * 8);
                if (USE_T)
                    pft[it] = *(const uint4*)(QbT + (r << 10) + (mt + 1) * 64 + kb0 * 8);
            }
        }

        f32x16 accT[2];
        #pragma unroll
        for (int t = 0; t < 2; ++t)
            #pragma unroll
            for (int e = 0; e < 16; ++e) accT[t][e] = 0.f;
        #pragma unroll
        for (int ks = 0; ks < 4; ++ks) {
            #pragma unroll
            for (int t = 0; t < 2; ++t) {
                const bf16x8 am = *(const bf16x8*)(&sQm[cur][(t * 32 + l31) * LDT + ks * 16 + hi * 8]);
                accT[t] = mfma32(am, bq[ks], accT[t]);
            }
        }

        bf16x8 pa[4];
        #pragma unroll
        for (int t = 0; t < 2; ++t) {
            f32x4 vf[4];
            #pragma unroll
            for (int g = 0; g < 4; ++g)
                vf[g] = *(const f32x4*)(&sv[mt * 64 + t * 32 + g * 8 + hi * 4]);
            float p[16];
            #pragma unroll
            for (int r = 0; r < 16; ++r)
                p[r] = __builtin_amdgcn_exp2f(
                         fmaf(accT[t][r], SCALE2, u2p + vf[r >> 2][r & 3]));
            #pragma unroll
            for (int kk = 0; kk < 2; ++kk) {
                const int rb = kk * 8;
                unsigned X0 = cvtpk(p[rb + 0], p[rb + 1]);
                unsigned Y0 = cvtpk(p[rb + 4], p[rb + 5]);
                unsigned X1 = cvtpk(p[rb + 2], p[rb + 3]);
                unsigned Y1 = cvtpk(p[rb + 6], p[rb + 7]);
                uint32x2 s0 = __builtin_amdgcn_permlane32_swap(X0, Y0, false, false);
                uint32x2 s1 = __builtin_amdgcn_permlane32_swap(X1, Y1, false, false);
                union { unsigned wd[4]; bf16x8 v8; } u4;
                u4.wd[0] = s0[0]; u4.wd[1] = s1[0]; u4.wd[2] = s0[1]; u4.wd[3] = s1[1];
                pa[t * 2 + kk] = u4.v8;
            }
        }

        #pragma unroll
        for (int ks = 0; ks < 4; ++ks)
            #pragma unroll
            for (int dt = 0; dt < 2; ++dt) {
                const bf16x8 bt = *(const bf16x8*)(&sQmT[cur][(dt * 32 + l31) * LDT + ks * 16 + hi * 8]);
                accO[dt] = mfma32(pa[ks], bt, accO[dt]);
            }

        if (mt < 15) {
            #pragma unroll
            for (int it = 0; it < 2; ++it) {
                const int r = it * 32 + r0;
                *(uint4*)(&sQm[cur ^ 1][r * LDT + kb0 * 8]) = pfm[it];
                if (USE_T) {
                    *(uint4*)(&sQmT[cur ^ 1][r * LDT + kb0 * 8]) = pft[it];
                } else {
                    union { uint4 q; bf16 e[8]; } cv; cv.q = pfm[it];
                    #pragma unroll
                    for (int j = 0; j < 8; ++j)
                        sQmT[cur ^ 1][(kb0 * 8 + j) * LDT + r] = cv.e[j];
                }
            }
        }
        __syncthreads();
    }

    const int hh = bh >> 3, bb = bh & 7;
    #pragma unroll
    for (int dt = 0; dt < 2; ++dt) {
        const int dcol = dt * 32 + l31;
        #pragma unroll
        for (int r = 0; r < 16; ++r) {
            const int irow = w * 32 + (r & 3) + 8 * (r >> 2) + 4 * hi;
            const float o = (float)sQi[irow * LDT + dcol] + accO[dt][r];
            O[((size_t)(bb * 1024 + rowTile + irow) << 9) + (hh << 6) + dcol] = o;
        }
    }
}

// ---------------------------------------------------------------------------
// LayerNorm over 512 (eps 1e-5, biased var): ONE WAVE PER ROW, 4 rows/block.
// 8 elems/lane, pure shfl_xor reduce, no LDS/barrier. grid 2048 x 256.
// ---------------------------------------------------------------------------
template<typename OutT>
__global__ __launch_bounds__(256)
void ln_kernel(const float* __restrict__ X, const float* __restrict__ g,
               const float* __restrict__ bb, OutT* __restrict__ out)
{
    const int row = blockIdx.x * 4 + (threadIdx.x >> 6);
    const int lane = threadIdx.x & 63;
    const float* x = X + (size_t)row * 512 + lane * 8;
    const float4 a0 = *(const float4*)x;
    const float4 a1 = *(const float4*)(x + 4);
    float s  = a0.x + a0.y + a0.z + a0.w + a1.x + a1.y + a1.z + a1.w;
    float ss = a0.x*a0.x + a0.y*a0.y + a0.z*a0.z + a0.w*a0.w
             + a1.x*a1.x + a1.y*a1.y + a1.z*a1.z + a1.w*a1.w;
    #pragma unroll
    for (int off = 32; off; off >>= 1) {
        s  += __shfl_xor(s, off);
        ss += __shfl_xor(ss, off);
    }
    const float mean = s * (1.f / 512.f);
    const float rstd = rsqrtf(ss * (1.f / 512.f) - mean * mean + 1e-5f);
    const int c = lane * 8;
    const float4 g0 = *(const float4*)(g + c),  g1 = *(const float4*)(g + c + 4);
    const float4 b0 = *(const float4*)(bb + c), b1 = *(const float4*)(bb + c + 4);
    float y[8];
    y[0] = (a0.x - mean) * rstd * g0.x + b0.x;
    y[1] = (a0.y - mean) * rstd * g0.y + b0.y;
    y[2] = (a0.z - mean) * rstd * g0.z + b0.z;
    y[3] = (a0.w - mean) * rstd * g0.w + b0.w;
    y[4] = (a1.x - mean) * rstd * g1.x + b1.x;
    y[5] = (a1.y - mean) * rstd * g1.y + b1.y;
    y[6] = (a1.z - mean) * rstd * g1.z + b1.z;
    y[7] = (a1.w - mean) * rstd * g1.w + b1.w;
    if constexpr (sizeof(OutT) == 2) {
        bf16x8 h;
        #pragma unroll
        for (int j = 0; j < 8; ++j) h[j] = (bf16)y[j];
        *(bf16x8*)((bf16*)out + (size_t)row * 512 + c) = h;
    } else {
        float4 o0 = {y[0], y[1], y[2], y[3]};
        float4 o1 = {y[4], y[5], y[6], y[7]};
        *(float4*)((float*)out + (size_t)row * 512 + c)     = o0;
        *(float4*)((float*)out + (size_t)row * 512 + c + 4) = o1;
    }
}

// ---------------------------------------------------------------------------
extern "C" void kernel_launch(void* const* d_in, const int* in_sizes, int n_in,
                              void* d_out, int out_size, void* d_ws, size_t ws_size,
                              hipStream_t stream)
{
    const float* Q  = (const float*)d_in[0];
    // d_in[1] = K: accepted but unused by the reference
    const float* Wq = (const float*)d_in[2];
    const float* bq = (const float*)d_in[3];
    const float* Wo = (const float*)d_in[4];
    const float* bo = (const float*)d_in[5];
    const float* g0 = (const float*)d_in[6];
    const float* b0 = (const float*)d_in[7];
    const float* g1 = (const float*)d_in[8];
    const float* b1 = (const float*)d_in[9];

    char* ws = (char*)d_ws;
    const bool useT = ws_size >= (size_t)34078720;

    bf16 *Qh, *QhT, *X0, *Wqb, *Wob;
    float *u, *v, *Obuf;
    if (useT) {
        Qh   = (bf16*)ws;                        // [64][1024][64] bf16 : 8 MB
        QhT  = (bf16*)(ws + 8388608);            // [64][64][1024] bf16 : 8 MB
        X0   = (bf16*)(ws + 8388608);            // aliases QhT (dead after av)
        u    = (float*)(ws + 16777216);          // 256 KB
        v    = (float*)(ws + 17039360);          // 256 KB
        Obuf = (float*)(ws + 17301504);          // 16 MB (O, reused as T)
        Wqb  = (bf16*)(ws + 16777216);           // 512 KB, aliases u+v (dead until lse)
        Wob  = (bf16*)ws;                        // aliases Qh (dead after av)
    } else {
        Qh   = (bf16*)ws;
        QhT  = nullptr;
        X0   = (bf16*)ws;                        // aliases Qh
        u    = (float*)(ws + 8388608);
        v    = (float*)(ws + 8650752);
        Obuf = (float*)(ws + 8912896);
        Wqb  = (bf16*)(ws + 8388608);            // aliases u+v (dead until lse)
        Wob  = (bf16*)(ws + 8388608);            // aliases u+v (dead after av)
    }

    cvtw_kernel<<<128, 256, 0, stream>>>(Wq, Wqb);
    gemm_kernel<0><<<dim3(8, 128), 256, 0, stream>>>(Q, Wqb, bq, nullptr, Qh, QhT, nullptr);
    sink_lse_kernel<0><<<dim3(16, 64), 256, 0, stream>>>(Qh, nullptr, u);
    sink_lse_kernel<1><<<dim3(16, 64), 256, 0, stream>>>(Qh, u, v);
    if (useT)
        sink_av_kernel<1><<<dim3(8, 64), 256, 0, stream>>>(Qh, QhT, u, v, Obuf);
    else
        sink_av_kernel<0><<<dim3(8, 64), 256, 0, stream>>>(Qh, Qh, u, v, Obuf);
    cvtw_kernel<<<128, 256, 0, stream>>>(Wo, Wob);
    ln_kernel<bf16><<<2048, 256, 0, stream>>>(Obuf, g0, b0, X0);
    gemm_kernel<1><<<dim3(8, 128), 256, 0, stream>>>(X0, Wob, bo, X0, nullptr, nullptr, Obuf);
    ln_kernel<float><<<2048, 256, 0, stream>>>(Obuf, g1, b1, (float*)d_out);
}

// Round 12
// 191.509 us; speedup vs baseline: 1.0237x; 1.0237x over previous
//
#include <hip/hip_runtime.h>
#include <hip/hip_bf16.h>

typedef __bf16 bf16;
typedef __bf16 bf16x4 __attribute__((ext_vector_type(4)));
typedef __bf16 bf16x8 __attribute__((ext_vector_type(8)));
typedef float  f32x4  __attribute__((ext_vector_type(4)));
typedef float  f32x16 __attribute__((ext_vector_type(16)));
typedef unsigned int uint32x2 __attribute__((ext_vector_type(2)));

#define DEVI static __device__ __forceinline__

constexpr float SCALE2  = 0.063758716f;           // log2(e)/sqrt(512)
constexpr float L2MU    = -9.9999852f;            // log2(1/1024 + 1e-8)
constexpr int   LDT     = 72;                     // padded LDS row stride (bf16 elems)

DEVI f32x4 mfma16(bf16x8 a, bf16x8 b, f32x4 c) {
    return __builtin_amdgcn_mfma_f32_16x16x32_bf16(a, b, c, 0, 0, 0);
}
DEVI f32x16 mfma32(bf16x8 a, bf16x8 b, f32x16 c) {
    return __builtin_amdgcn_mfma_f32_32x32x16_bf16(a, b, c, 0, 0, 0);
}
// packed f32->bf16 pair (no builtin on gfx950; m240)
DEVI unsigned cvtpk(float lo, float hi) {
    unsigned r;
    asm("v_cvt_pk_bf16_f32 %0, %1, %2" : "=v"(r) : "v"(lo), "v"(hi));
    return r;
}

// load 8 fp32, convert to bf16x8
DEVI bf16x8 cvt8(const float* __restrict__ p) {
    const float4 f0 = *(const float4*)p;
    const float4 f1 = *(const float4*)(p + 4);
    bf16x8 h;
    h[0] = (bf16)f0.x; h[1] = (bf16)f0.y; h[2] = (bf16)f0.z; h[3] = (bf16)f0.w;
    h[4] = (bf16)f1.x; h[5] = (bf16)f1.y; h[6] = (bf16)f1.z; h[7] = (bf16)f1.w;
    return h;
}

// ---------------------------------------------------------------------------
// one-shot fp32 -> bf16 weight conversion (512x512), grid 128 x 256
// ---------------------------------------------------------------------------
__global__ __launch_bounds__(256)
void cvtw_kernel(const float* __restrict__ W, bf16* __restrict__ Wb)
{
    const int i = (blockIdx.x * 256 + threadIdx.x) * 8;
    *(bf16x8*)(&Wb[i]) = cvt8(W + i);
}

// ---------------------------------------------------------------------------
// GEMM: C[row][col] = sum_k A[row][k]*Bb[col][k] + bias[col]   (Bb bf16)
// EPI==0: A fp32 (=Q). scatter bf16 to head-major Qh [64][1024][64] and
//         transposed QhT [64][64][1024] (b64 packed stores).
// EPI==1: A bf16 (=X0). T[row][col] = X0[row][col] + relu(C)  (fp32 out)
// M=8192, N=512, K=512. Tile 128x64, BK=64, 4 waves 2x2, wave = 64x32
// (acc[4][2]): 12 ds_reads feed 16 mfma per K-step (was 8:8) -> 25% less
// LDS traffic per output. LDS 55296 B -> 2 blocks/CU (throughput-bound,
// dbuf register prefetch hides HBM). Grid (8,64)=512, XCD swizzle.
// ---------------------------------------------------------------------------
template<int EPI>
__global__ __launch_bounds__(256)
void gemm_kernel(const void* __restrict__ Ap, const bf16* __restrict__ Bb,
                 const float* __restrict__ bias, const bf16* __restrict__ X0,
                 bf16* __restrict__ outQh, bf16* __restrict__ outQhT,
                 float* __restrict__ outT)
{
    __shared__ bf16 sA[2][128 * LDT];       // 36864 B
    __shared__ bf16 sB[2][64 * LDT];        // 18432 B
    const int tid = threadIdx.x;
    const int lin = blockIdx.y * 8 + blockIdx.x;        // grid (8,64) = 512
    const int wk  = ((lin & 7) << 6) | (lin >> 3);      // 64 blocks/XCD chunk
    const int rowBase = (wk >> 3) * 128;
    const int colBase = (wk & 7) * 64;
    const int w = tid >> 6, lane = tid & 63, quad = lane >> 4, l16 = lane & 15;
    const int wr = (w >> 1) * 64, wc = (w & 1) * 32;
    const int r0 = tid >> 3, kb0 = tid & 7;             // staging coords

    f32x4 acc[4][2];
    #pragma unroll
    for (int i = 0; i < 4; ++i)
        #pragma unroll
        for (int j = 0; j < 2; ++j)
            #pragma unroll
            for (int e = 0; e < 4; ++e) acc[i][j][e] = 0.f;

    // stage kt=0 into buffer 0
    #pragma unroll
    for (int it = 0; it < 4; ++it) {        // A: 128 rows x 8 chunks
        const int idx = it * 256 + tid;
        const int r = idx >> 3, kb = idx & 7;
        if (EPI == 0)
            *(bf16x8*)(&sA[0][r * LDT + kb * 8]) =
                cvt8((const float*)Ap + (size_t)(rowBase + r) * 512 + kb * 8);
        else
            *(uint4*)(&sA[0][r * LDT + kb * 8]) =
                *(const uint4*)((const bf16*)Ap + (size_t)(rowBase + r) * 512 + kb * 8);
    }
    #pragma unroll
    for (int it = 0; it < 2; ++it) {        // B: 64 rows x 8 chunks
        const int r = it * 32 + r0;
        *(uint4*)(&sB[0][r * LDT + kb0 * 8]) =
            *(const uint4*)(Bb + (size_t)(colBase + r) * 512 + kb0 * 8);
    }
    __syncthreads();

    for (int kt8 = 0; kt8 < 8; ++kt8) {
        const int cur = kt8 & 1;
        float4 pfa[4][2];
        uint4  pfa16[4], pfb[2];
        if (kt8 < 7) {
            const int kn = (kt8 + 1) * 64;
            #pragma unroll
            for (int it = 0; it < 4; ++it) {
                const int idx = it * 256 + tid;
                const int r = idx >> 3, kb = idx & 7;
                if (EPI == 0) {
                    const float* ap = (const float*)Ap + (size_t)(rowBase + r) * 512 + kn + kb * 8;
                    pfa[it][0] = *(const float4*)ap;
                    pfa[it][1] = *(const float4*)(ap + 4);
                } else {
                    pfa16[it] = *(const uint4*)((const bf16*)Ap + (size_t)(rowBase + r) * 512 + kn + kb * 8);
                }
            }
            #pragma unroll
            for (int it = 0; it < 2; ++it) {
                const int r = it * 32 + r0;
                pfb[it] = *(const uint4*)(Bb + (size_t)(colBase + r) * 512 + kn + kb0 * 8);
            }
        }

        #pragma unroll
        for (int kk = 0; kk < 2; ++kk) {
            bf16x8 a[4], b[2];
            #pragma unroll
            for (int i = 0; i < 4; ++i)
                a[i] = *(const bf16x8*)(&sA[cur][(wr + i * 16 + l16) * LDT + kk * 32 + quad * 8]);
            #pragma unroll
            for (int j = 0; j < 2; ++j)
                b[j] = *(const bf16x8*)(&sB[cur][(wc + j * 16 + l16) * LDT + kk * 32 + quad * 8]);
            #pragma unroll
            for (int i = 0; i < 4; ++i)
                #pragma unroll
                for (int j = 0; j < 2; ++j)
                    acc[i][j] = mfma16(a[i], b[j], acc[i][j]);
        }

        if (kt8 < 7) {
            #pragma unroll
            for (int it = 0; it < 4; ++it) {
                const int idx = it * 256 + tid;
                const int r = idx >> 3, kb = idx & 7;
                if (EPI == 0) {
                    bf16x8 h;
                    h[0] = (bf16)pfa[it][0].x; h[1] = (bf16)pfa[it][0].y;
                    h[2] = (bf16)pfa[it][0].z; h[3] = (bf16)pfa[it][0].w;
                    h[4] = (bf16)pfa[it][1].x; h[5] = (bf16)pfa[it][1].y;
                    h[6] = (bf16)pfa[it][1].z; h[7] = (bf16)pfa[it][1].w;
                    *(bf16x8*)(&sA[cur ^ 1][r * LDT + kb * 8]) = h;
                } else {
                    *(uint4*)(&sA[cur ^ 1][r * LDT + kb * 8]) = pfa16[it];
                }
            }
            #pragma unroll
            for (int it = 0; it < 2; ++it) {
                const int r = it * 32 + r0;
                *(uint4*)(&sB[cur ^ 1][r * LDT + kb0 * 8]) = pfb[it];
            }
        }
        __syncthreads();
    }

    #pragma unroll
    for (int i = 0; i < 4; ++i) {
        #pragma unroll
        for (int j = 0; j < 2; ++j) {
            const int col = colBase + wc + j * 16 + l16;
            const float bv = bias[col];
            if (EPI == 0) {
                const int hh = col >> 6, jj = col & 63;
                const int rowA = rowBase + wr + i * 16 + quad * 4;
                const int bb = rowA >> 10, iib = rowA & 1023;
                const int bhh = (hh << 3) + bb;
                bf16x4 pk;
                #pragma unroll
                for (int rg = 0; rg < 4; ++rg) {
                    const float z = acc[i][j][rg] + bv;
                    pk[rg] = (bf16)z;
                    outQh[((size_t)(bhh * 1024 + iib + rg) << 6) + jj] = (bf16)z;
                }
                if (outQhT)
                    *(bf16x4*)(&outQhT[(((size_t)bhh * 64 + jj) << 10) + iib]) = pk;
            } else {
                #pragma unroll
                for (int rg = 0; rg < 4; ++rg) {
                    const int row = rowBase + wr + i * 16 + quad * 4 + rg;
                    const float z = acc[i][j][rg] + bv;
                    const float x0 = (float)X0[(size_t)row * 512 + col];
                    outT[(size_t)row * 512 + col] = x0 + fmaxf(z, 0.f);
                }
            }
        }
    }
}

// ---------------------------------------------------------------------------
// Sinkhorn LSE passes over S = Q_ Q_^T / sqrt(512)  (S symmetric), log2-domain:
// ADD_U==0: out[i] = L2MU - log2(sum_m 2^(S[i][m]*s2))             (= u2)
// ADD_U==1: out[m] = L2MU - log2(sum_i 2^(S[m][i]*s2 + u2[i]))     (= v2)
// 64 rows/block, 4 waves x 16 rows; grid (16, 64) = 1024 blocks = 4/CU.
// Qi A-frags are mt-invariant -> hoisted to registers (no sQi LDS).
// (round-4/5/9 harness-proven version)
// ---------------------------------------------------------------------------
template<int ADD_U>
__global__ __launch_bounds__(256, 4)
void sink_lse_kernel(const bf16* __restrict__ Qh, const float* __restrict__ uin,
                     float* __restrict__ out)
{
    __shared__ bf16 sQm[2][64 * LDT];       // 18432 B
    __shared__ float su[1024];              //  4096 B
    const int tid = threadIdx.x;
    const int lin = blockIdx.y * 16 + blockIdx.x;
    const int wk  = ((lin & 7) << 7) | (lin >> 3);
    const int bh = wk >> 4;
    const int rowTile = (wk & 15) * 64;
    const bf16* Qb = Qh + ((size_t)bh << 16);   // bh*1024*64

    if (ADD_U)
        *(float4*)(&su[tid * 4]) = *(const float4*)(uin + (bh << 10) + tid * 4);

    const int r0 = tid >> 3, kb0 = tid & 7;
    #pragma unroll
    for (int it = 0; it < 2; ++it)
        *(uint4*)(&sQm[0][(it * 32 + r0) * LDT + kb0 * 8]) =
            *(const uint4*)(Qb + ((it * 32 + r0) << 6) + kb0 * 8);

    const int w = tid >> 6, lane = tid & 63, quad = lane >> 4, l16 = lane & 15;
    bf16x8 afr[2];
    #pragma unroll
    for (int kk = 0; kk < 2; ++kk)
        afr[kk] = *(const bf16x8*)(Qb + ((rowTile + w * 16 + l16) << 6) + kk * 32 + quad * 8);
    __syncthreads();

    float rsum[4] = {0.f, 0.f, 0.f, 0.f};

    for (int mt = 0; mt < 16; ++mt) {
        const int cur = mt & 1;
        uint4 pf[2];
        if (mt < 15) {
            #pragma unroll
            for (int it = 0; it < 2; ++it)
                pf[it] = *(const uint4*)(Qb + (((mt + 1) * 64 + it * 32 + r0) << 6) + kb0 * 8);
        }

        f32x4 acc[4];
        #pragma unroll
        for (int ct = 0; ct < 4; ++ct)
            #pragma unroll
            for (int e = 0; e < 4; ++e) acc[ct][e] = 0.f;

        #pragma unroll
        for (int kk = 0; kk < 2; ++kk) {
            bf16x8 bfr[4];
            #pragma unroll
            for (int ct = 0; ct < 4; ++ct)
                bfr[ct] = *(const bf16x8*)(&sQm[cur][(ct * 16 + l16) * LDT + kk * 32 + quad * 8]);
            #pragma unroll
            for (int ct = 0; ct < 4; ++ct)
                acc[ct] = mfma16(afr[kk], bfr[ct], acc[ct]);
        }
        #pragma unroll
        for (int ct = 0; ct < 4; ++ct) {
            const float uadd = ADD_U ? su[mt * 64 + ct * 16 + l16] : 0.f;
            #pragma unroll
            for (int rg = 0; rg < 4; ++rg)
                rsum[rg] += __builtin_amdgcn_exp2f(fmaf(acc[ct][rg], SCALE2, uadd));
        }

        if (mt < 15) {
            #pragma unroll
            for (int it = 0; it < 2; ++it)
                *(uint4*)(&sQm[cur ^ 1][(it * 32 + r0) * LDT + kb0 * 8]) = pf[it];
        }
        __syncthreads();
    }
    #pragma unroll
    for (int off = 1; off < 16; off <<= 1)
        #pragma unroll
        for (int rg = 0; rg < 4; ++rg)
            rsum[rg] += __shfl_xor(rsum[rg], off);

    if (l16 == 0) {
        #pragma unroll
        for (int rg = 0; rg < 4; ++rg)
            out[(bh << 10) + rowTile + w * 16 + quad * 4 + rg] =
                L2MU - __builtin_amdgcn_logf(rsum[rg]);
    }
}

// ---------------------------------------------------------------------------
// O_ = Q_ + A Q_,  A[i][m] = 2^(S[i][m]*s2 + u2[i] + v2[m] + 10).
// Swapped 32x32x16 QK^T; PV A-frags in-register (cvt_pk + permlane32_swap).
// 128 rows/block, 4 waves x 32 rows; grid (8, 64), XCD-swizzled.
// Round-9 harness-proven version (194.4 us): sQi PADDED, sv in LDS,
// bq hoisted, __launch_bounds__(256,2). NO-TOUCH list: unpadded sQi /
// global-vf (R8+R10 corrupt, absmax 8.016) and (256,3) cap (R7 corrupt).
// ---------------------------------------------------------------------------
template<int USE_T>
__global__ __launch_bounds__(256, 2)
void sink_av_kernel(const bf16* __restrict__ Qh, const bf16* __restrict__ QhT,
                    const float* __restrict__ u, const float* __restrict__ v,
                    float* __restrict__ O)
{
    __shared__ bf16 sQi[128 * LDT];         // 18432 B
    __shared__ bf16 sQm[2][64 * LDT];       // 18432 B
    __shared__ bf16 sQmT[2][64 * LDT];      // 18432 B  [dcol][m]
    __shared__ float sv[1024];              //  4096 B   -> total 59392 B
    const int tid = threadIdx.x;
    const int lin = blockIdx.y * 8 + blockIdx.x;
    const int wk  = ((lin & 7) << 6) | (lin >> 3);
    const int bh = wk >> 3;
    const int rowTile = (wk & 7) * 128;
    const bf16* Qb = Qh + ((size_t)bh << 16);
    const bf16* QbT = QhT + ((size_t)bh << 16);
    const int w = tid >> 6, lane = tid & 63, hi = lane >> 5, l31 = lane & 31;
    const int r0 = tid >> 3, kb0 = tid & 7;

    #pragma unroll
    for (int it = 0; it < 4; ++it) {
        int idx = it * 256 + tid;
        int r = idx >> 3, kb = idx & 7;
        *(uint4*)(&sQi[r * LDT + kb * 8]) =
            *(const uint4*)(Qb + ((rowTile + r) << 6) + kb * 8);
    }
    *(float4*)(&sv[tid * 4]) = *(const float4*)(v + (bh << 10) + tid * 4);
    const float u2p = u[(bh << 10) + rowTile + w * 32 + l31] + 10.f;

    #pragma unroll
    for (int it = 0; it < 2; ++it) {
        const int r = it * 32 + r0;
        uint4 val = *(const uint4*)(Qb + (r << 6) + kb0 * 8);
        *(uint4*)(&sQm[0][r * LDT + kb0 * 8]) = val;
        if (USE_T) {
            *(uint4*)(&sQmT[0][r * LDT + kb0 * 8]) =
                *(const uint4*)(QbT + (r << 10) + kb0 * 8);
        } else {
            union { uint4 q; bf16 e[8]; } cv; cv.q = val;
            #pragma unroll
            for (int j = 0; j < 8; ++j)
                sQmT[0][(kb0 * 8 + j) * LDT + r] = cv.e[j];
        }
    }
    __syncthreads();

    // hoist the mt-invariant Qi B-frags (row w*32 + l31) to registers
    bf16x8 bq[4];
    #pragma unroll
    for (int ks = 0; ks < 4; ++ks)
        bq[ks] = *(const bf16x8*)(&sQi[(w * 32 + l31) * LDT + ks * 16 + hi * 8]);

    f32x16 accO[2];
    #pragma unroll
    for (int dt = 0; dt < 2; ++dt)
        #pragma unroll
        for (int e = 0; e < 16; ++e) accO[dt][e] = 0.f;

    for (int mt = 0; mt < 16; ++mt) {
        const int cur = mt & 1;
        uint4 pfm[2], pft[2];
        if (mt < 15) {
            #pragma unroll
            for (int it = 0; it < 2; ++it) {
                const int r = it * 32 + r0;
                pfm[it] = *(const uint4*)(Qb + (((mt + 1) * 64 + r) << 6) + kb0 * 8);
                if (USE_T)
                    pft[it] = *(const uint4*)(QbT + (r << 10) + (mt + 1) * 64 + kb0 * 8);
            }
        }

        f32x16 accT[2];
        #pragma unroll
        for (int t = 0; t < 2; ++t)
            #pragma unroll
            for (int e = 0; e < 16; ++e) accT[t][e] = 0.f;
        #pragma unroll
        for (int ks = 0; ks < 4; ++ks) {
            #pragma unroll
            for (int t = 0; t < 2; ++t) {
                const bf16x8 am = *(const bf16x8*)(&sQm[cur][(t * 32 + l31) * LDT + ks * 16 + hi * 8]);
                accT[t] = mfma32(am, bq[ks], accT[t]);
            }
        }

        bf16x8 pa[4];
        #pragma unroll
        for (int t = 0; t < 2; ++t) {
            f32x4 vf[4];
            #pragma unroll
            for (int g = 0; g < 4; ++g)
                vf[g] = *(const f32x4*)(&sv[mt * 64 + t * 32 + g * 8 + hi * 4]);
            float p[16];
            #pragma unroll
            for (int r = 0; r < 16; ++r)
                p[r] = __builtin_amdgcn_exp2f(
                         fmaf(accT[t][r], SCALE2, u2p + vf[r >> 2][r & 3]));
            #pragma unroll
            for (int kk = 0; kk < 2; ++kk) {
                const int rb = kk * 8;
                unsigned X0 = cvtpk(p[rb + 0], p[rb + 1]);
                unsigned Y0 = cvtpk(p[rb + 4], p[rb + 5]);
                unsigned X1 = cvtpk(p[rb + 2], p[rb + 3]);
                unsigned Y1 = cvtpk(p[rb + 6], p[rb + 7]);
                uint32x2 s0 = __builtin_amdgcn_permlane32_swap(X0, Y0, false, false);
                uint32x2 s1 = __builtin_amdgcn_permlane32_swap(X1, Y1, false, false);
                union { unsigned wd[4]; bf16x8 v8; } u4;
                u4.wd[0] = s0[0]; u4.wd[1] = s1[0]; u4.wd[2] = s0[1]; u4.wd[3] = s1[1];
                pa[t * 2 + kk] = u4.v8;
            }
        }

        #pragma unroll
        for (int ks = 0; ks < 4; ++ks)
            #pragma unroll
            for (int dt = 0; dt < 2; ++dt) {
                const bf16x8 bt = *(const bf16x8*)(&sQmT[cur][(dt * 32 + l31) * LDT + ks * 16 + hi * 8]);
                accO[dt] = mfma32(pa[ks], bt, accO[dt]);
            }

        if (mt < 15) {
            #pragma unroll
            for (int it = 0; it < 2; ++it) {
                const int r = it * 32 + r0;
                *(uint4*)(&sQm[cur ^ 1][r * LDT + kb0 * 8]) = pfm[it];
                if (USE_T) {
                    *(uint4*)(&sQmT[cur ^ 1][r * LDT + kb0 * 8]) = pft[it];
                } else {
                    union { uint4 q; bf16 e[8]; } cv; cv.q = pfm[it];
                    #pragma unroll
                    for (int j = 0; j < 8; ++j)
                        sQmT[cur ^ 1][(kb0 * 8 + j) * LDT + r] = cv.e[j];
                }
            }
        }
        __syncthreads();
    }

    const int hh = bh >> 3, bb = bh & 7;
    #pragma unroll
    for (int dt = 0; dt < 2; ++dt) {
        const int dcol = dt * 32 + l31;
        #pragma unroll
        for (int r = 0; r < 16; ++r) {
            const int irow = w * 32 + (r & 3) + 8 * (r >> 2) + 4 * hi;
            const float o = (float)sQi[irow * LDT + dcol] + accO[dt][r];
            O[((size_t)(bb * 1024 + rowTile + irow) << 9) + (hh << 6) + dcol] = o;
        }
    }
}

// ---------------------------------------------------------------------------
// LayerNorm over 512 (eps 1e-5, biased var): ONE WAVE PER ROW, 4 rows/block.
// 8 elems/lane, pure shfl_xor reduce, no LDS/barrier. grid 2048 x 256.
// ---------------------------------------------------------------------------
template<typename OutT>
__global__ __launch_bounds__(256)
void ln_kernel(const float* __restrict__ X, const float* __restrict__ g,
               const float* __restrict__ bb, OutT* __restrict__ out)
{
    const int row = blockIdx.x * 4 + (threadIdx.x >> 6);
    const int lane = threadIdx.x & 63;
    const float* x = X + (size_t)row * 512 + lane * 8;
    const float4 a0 = *(const float4*)x;
    const float4 a1 = *(const float4*)(x + 4);
    float s  = a0.x + a0.y + a0.z + a0.w + a1.x + a1.y + a1.z + a1.w;
    float ss = a0.x*a0.x + a0.y*a0.y + a0.z*a0.z + a0.w*a0.w
             + a1.x*a1.x + a1.y*a1.y + a1.z*a1.z + a1.w*a1.w;
    #pragma unroll
    for (int off = 32; off; off >>= 1) {
        s  += __shfl_xor(s, off);
        ss += __shfl_xor(ss, off);
    }
    const float mean = s * (1.f / 512.f);
    const float rstd = rsqrtf(ss * (1.f / 512.f) - mean * mean + 1e-5f);
    const int c = lane * 8;
    const float4 g0 = *(const float4*)(g + c),  g1 = *(const float4*)(g + c + 4);
    const float4 b0 = *(const float4*)(bb + c), b1 = *(const float4*)(bb + c + 4);
    float y[8];
    y[0] = (a0.x - mean) * rstd * g0.x + b0.x;
    y[1] = (a0.y - mean) * rstd * g0.y + b0.y;
    y[2] = (a0.z - mean) * rstd * g0.z + b0.z;
    y[3] = (a0.w - mean) * rstd * g0.w + b0.w;
    y[4] = (a1.x - mean) * rstd * g1.x + b1.x;
    y[5] = (a1.y - mean) * rstd * g1.y + b1.y;
    y[6] = (a1.z - mean) * rstd * g1.z + b1.z;
    y[7] = (a1.w - mean) * rstd * g1.w + b1.w;
    if constexpr (sizeof(OutT) == 2) {
        bf16x8 h;
        #pragma unroll
        for (int j = 0; j < 8; ++j) h[j] = (bf16)y[j];
        *(bf16x8*)((bf16*)out + (size_t)row * 512 + c) = h;
    } else {
        float4 o0 = {y[0], y[1], y[2], y[3]};
        float4 o1 = {y[4], y[5], y[6], y[7]};
        *(float4*)((float*)out + (size_t)row * 512 + c)     = o0;
        *(float4*)((float*)out + (size_t)row * 512 + c + 4) = o1;
    }
}

// ---------------------------------------------------------------------------
extern "C" void kernel_launch(void* const* d_in, const int* in_sizes, int n_in,
                              void* d_out, int out_size, void* d_ws, size_t ws_size,
                              hipStream_t stream)
{
    const float* Q  = (const float*)d_in[0];
    // d_in[1] = K: accepted but unused by the reference
    const float* Wq = (const float*)d_in[2];
    const float* bq = (const float*)d_in[3];
    const float* Wo = (const float*)d_in[4];
    const float* bo = (const float*)d_in[5];
    const float* g0 = (const float*)d_in[6];
    const float* b0 = (const float*)d_in[7];
    const float* g1 = (const float*)d_in[8];
    const float* b1 = (const float*)d_in[9];

    char* ws = (char*)d_ws;
    const bool useT = ws_size >= (size_t)34078720;

    bf16 *Qh, *QhT, *X0, *Wqb, *Wob;
    float *u, *v, *Obuf;
    if (useT) {
        Qh   = (bf16*)ws;                        // [64][1024][64] bf16 : 8 MB
        QhT  = (bf16*)(ws + 8388608);            // [64][64][1024] bf16 : 8 MB
        X0   = (bf16*)(ws + 8388608);            // aliases QhT (dead after av)
        u    = (float*)(ws + 16777216);          // 256 KB
        v    = (float*)(ws + 17039360);          // 256 KB
        Obuf = (float*)(ws + 17301504);          // 16 MB (O, reused as T)
        Wqb  = (bf16*)(ws + 16777216);           // 512 KB, aliases u+v (dead until lse)
        Wob  = (bf16*)ws;                        // aliases Qh (dead after av)
    } else {
        Qh   = (bf16*)ws;
        QhT  = nullptr;
        X0   = (bf16*)ws;                        // aliases Qh
        u    = (float*)(ws + 8388608);
        v    = (float*)(ws + 8650752);
        Obuf = (float*)(ws + 8912896);
        Wqb  = (bf16*)(ws + 8388608);            // aliases u+v (dead until lse)
        Wob  = (bf16*)(ws + 8388608);            // aliases u+v (dead after av)
    }

    cvtw_kernel<<<128, 256, 0, stream>>>(Wq, Wqb);
    gemm_kernel<0><<<dim3(8, 64), 256, 0, stream>>>(Q, Wqb, bq, nullptr, Qh, QhT, nullptr);
    sink_lse_kernel<0><<<dim3(16, 64), 256, 0, stream>>>(Qh, nullptr, u);
    sink_lse_kernel<1><<<dim3(16, 64), 256, 0, stream>>>(Qh, u, v);
    if (useT)
        sink_av_kernel<1><<<dim3(8, 64), 256, 0, stream>>>(Qh, QhT, u, v, Obuf);
    else
        sink_av_kernel<0><<<dim3(8, 64), 256, 0, stream>>>(Qh, Qh, u, v, Obuf);
    cvtw_kernel<<<128, 256, 0, stream>>>(Wo, Wob);
    ln_kernel<bf16><<<2048, 256, 0, stream>>>(Obuf, g0, b0, X0);
    gemm_kernel<1><<<dim3(8, 64), 256, 0, stream>>>(X0, Wob, bo, X0, nullptr, nullptr, Obuf);
    ln_kernel<float><<<2048, 256, 0, stream>>>(Obuf, g1, b1, (float*)d_out);
}

// Round 13
// 189.596 us; speedup vs baseline: 1.0340x; 1.0101x over previous
//
#include <hip/hip_runtime.h>
#include <hip/hip_bf16.h>

typedef __bf16 bf16;
typedef __bf16 bf16x4 __attribute__((ext_vector_type(4)));
typedef __bf16 bf16x8 __attribute__((ext_vector_type(8)));
typedef float  f32x4  __attribute__((ext_vector_type(4)));
typedef float  f32x16 __attribute__((ext_vector_type(16)));
typedef unsigned int uint32x2 __attribute__((ext_vector_type(2)));

#define DEVI static __device__ __forceinline__

constexpr float SCALE2  = 0.063758716f;           // log2(e)/sqrt(512)
constexpr float L2MU    = -9.9999852f;            // log2(1/1024 + 1e-8)
constexpr int   LDT     = 72;                     // padded LDS row stride (bf16 elems)

DEVI f32x4 mfma16(bf16x8 a, bf16x8 b, f32x4 c) {
    return __builtin_amdgcn_mfma_f32_16x16x32_bf16(a, b, c, 0, 0, 0);
}
DEVI f32x16 mfma32(bf16x8 a, bf16x8 b, f32x16 c) {
    return __builtin_amdgcn_mfma_f32_32x32x16_bf16(a, b, c, 0, 0, 0);
}
// packed f32->bf16 pair (no builtin on gfx950; m240)
DEVI unsigned cvtpk(float lo, float hi) {
    unsigned r;
    asm("v_cvt_pk_bf16_f32 %0, %1, %2" : "=v"(r) : "v"(lo), "v"(hi));
    return r;
}

// load 8 fp32, convert to bf16x8
DEVI bf16x8 cvt8(const float* __restrict__ p) {
    const float4 f0 = *(const float4*)p;
    const float4 f1 = *(const float4*)(p + 4);
    bf16x8 h;
    h[0] = (bf16)f0.x; h[1] = (bf16)f0.y; h[2] = (bf16)f0.z; h[3] = (bf16)f0.w;
    h[4] = (bf16)f1.x; h[5] = (bf16)f1.y; h[6] = (bf16)f1.z; h[7] = (bf16)f1.w;
    return h;
}

// ---------------------------------------------------------------------------
// one-shot fp32 -> bf16 weight conversion (512x512), grid 128 x 256
// ---------------------------------------------------------------------------
__global__ __launch_bounds__(256)
void cvtw_kernel(const float* __restrict__ W, bf16* __restrict__ Wb)
{
    const int i = (blockIdx.x * 256 + threadIdx.x) * 8;
    *(bf16x8*)(&Wb[i]) = cvt8(W + i);
}

// ---------------------------------------------------------------------------
// GEMM: C[row][col] = sum_k A[row][k]*Bb[col][k] + bias[col]   (Bb bf16)
// EPI==0: A fp32 (=Q). scatter bf16 to head-major Qh [64][1024][64] and
//         transposed QhT [64][64][1024] (b64 packed stores).
// EPI==1: A bf16 (=X0). T[row][col] = X0[row][col] + relu(C)  (fp32 out)
// M=8192, N=512, K=512. Tile 128x64, BK=64, 4 waves 2x2, wave = 64x32.
// (round-12 harness-proven version, 191.5 us)
// ---------------------------------------------------------------------------
template<int EPI>
__global__ __launch_bounds__(256)
void gemm_kernel(const void* __restrict__ Ap, const bf16* __restrict__ Bb,
                 const float* __restrict__ bias, const bf16* __restrict__ X0,
                 bf16* __restrict__ outQh, bf16* __restrict__ outQhT,
                 float* __restrict__ outT)
{
    __shared__ bf16 sA[2][128 * LDT];       // 36864 B
    __shared__ bf16 sB[2][64 * LDT];        // 18432 B
    const int tid = threadIdx.x;
    const int lin = blockIdx.y * 8 + blockIdx.x;        // grid (8,64) = 512
    const int wk  = ((lin & 7) << 6) | (lin >> 3);      // 64 blocks/XCD chunk
    const int rowBase = (wk >> 3) * 128;
    const int colBase = (wk & 7) * 64;
    const int w = tid >> 6, lane = tid & 63, quad = lane >> 4, l16 = lane & 15;
    const int wr = (w >> 1) * 64, wc = (w & 1) * 32;
    const int r0 = tid >> 3, kb0 = tid & 7;             // staging coords

    f32x4 acc[4][2];
    #pragma unroll
    for (int i = 0; i < 4; ++i)
        #pragma unroll
        for (int j = 0; j < 2; ++j)
            #pragma unroll
            for (int e = 0; e < 4; ++e) acc[i][j][e] = 0.f;

    // stage kt=0 into buffer 0
    #pragma unroll
    for (int it = 0; it < 4; ++it) {        // A: 128 rows x 8 chunks
        const int idx = it * 256 + tid;
        const int r = idx >> 3, kb = idx & 7;
        if (EPI == 0)
            *(bf16x8*)(&sA[0][r * LDT + kb * 8]) =
                cvt8((const float*)Ap + (size_t)(rowBase + r) * 512 + kb * 8);
        else
            *(uint4*)(&sA[0][r * LDT + kb * 8]) =
                *(const uint4*)((const bf16*)Ap + (size_t)(rowBase + r) * 512 + kb * 8);
    }
    #pragma unroll
    for (int it = 0; it < 2; ++it) {        // B: 64 rows x 8 chunks
        const int r = it * 32 + r0;
        *(uint4*)(&sB[0][r * LDT + kb0 * 8]) =
            *(const uint4*)(Bb + (size_t)(colBase + r) * 512 + kb0 * 8);
    }
    __syncthreads();

    for (int kt8 = 0; kt8 < 8; ++kt8) {
        const int cur = kt8 & 1;
        float4 pfa[4][2];
        uint4  pfa16[4], pfb[2];
        if (kt8 < 7) {
            const int kn = (kt8 + 1) * 64;
            #pragma unroll
            for (int it = 0; it < 4; ++it) {
                const int idx = it * 256 + tid;
                const int r = idx >> 3, kb = idx & 7;
                if (EPI == 0) {
                    const float* ap = (const float*)Ap + (size_t)(rowBase + r) * 512 + kn + kb * 8;
                    pfa[it][0] = *(const float4*)ap;
                    pfa[it][1] = *(const float4*)(ap + 4);
                } else {
                    pfa16[it] = *(const uint4*)((const bf16*)Ap + (size_t)(rowBase + r) * 512 + kn + kb * 8);
                }
            }
            #pragma unroll
            for (int it = 0; it < 2; ++it) {
                const int r = it * 32 + r0;
                pfb[it] = *(const uint4*)(Bb + (size_t)(colBase + r) * 512 + kn + kb0 * 8);
            }
        }

        #pragma unroll
        for (int kk = 0; kk < 2; ++kk) {
            bf16x8 a[4], b[2];
            #pragma unroll
            for (int i = 0; i < 4; ++i)
                a[i] = *(const bf16x8*)(&sA[cur][(wr + i * 16 + l16) * LDT + kk * 32 + quad * 8]);
            #pragma unroll
            for (int j = 0; j < 2; ++j)
                b[j] = *(const bf16x8*)(&sB[cur][(wc + j * 16 + l16) * LDT + kk * 32 + quad * 8]);
            #pragma unroll
            for (int i = 0; i < 4; ++i)
                #pragma unroll
                for (int j = 0; j < 2; ++j)
                    acc[i][j] = mfma16(a[i], b[j], acc[i][j]);
        }

        if (kt8 < 7) {
            #pragma unroll
            for (int it = 0; it < 4; ++it) {
                const int idx = it * 256 + tid;
                const int r = idx >> 3, kb = idx & 7;
                if (EPI == 0) {
                    bf16x8 h;
                    h[0] = (bf16)pfa[it][0].x; h[1] = (bf16)pfa[it][0].y;
                    h[2] = (bf16)pfa[it][0].z; h[3] = (bf16)pfa[it][0].w;
                    h[4] = (bf16)pfa[it][1].x; h[5] = (bf16)pfa[it][1].y;
                    h[6] = (bf16)pfa[it][1].z; h[7] = (bf16)pfa[it][1].w;
                    *(bf16x8*)(&sA[cur ^ 1][r * LDT + kb * 8]) = h;
                } else {
                    *(uint4*)(&sA[cur ^ 1][r * LDT + kb * 8]) = pfa16[it];
                }
            }
            #pragma unroll
            for (int it = 0; it < 2; ++it) {
                const int r = it * 32 + r0;
                *(uint4*)(&sB[cur ^ 1][r * LDT + kb0 * 8]) = pfb[it];
            }
        }
        __syncthreads();
    }

    #pragma unroll
    for (int i = 0; i < 4; ++i) {
        #pragma unroll
        for (int j = 0; j < 2; ++j) {
            const int col = colBase + wc + j * 16 + l16;
            const float bv = bias[col];
            if (EPI == 0) {
                const int hh = col >> 6, jj = col & 63;
                const int rowA = rowBase + wr + i * 16 + quad * 4;
                const int bb = rowA >> 10, iib = rowA & 1023;
                const int bhh = (hh << 3) + bb;
                bf16x4 pk;
                #pragma unroll
                for (int rg = 0; rg < 4; ++rg) {
                    const float z = acc[i][j][rg] + bv;
                    pk[rg] = (bf16)z;
                    outQh[((size_t)(bhh * 1024 + iib + rg) << 6) + jj] = (bf16)z;
                }
                if (outQhT)
                    *(bf16x4*)(&outQhT[(((size_t)bhh * 64 + jj) << 10) + iib]) = pk;
            } else {
                #pragma unroll
                for (int rg = 0; rg < 4; ++rg) {
                    const int row = rowBase + wr + i * 16 + quad * 4 + rg;
                    const float z = acc[i][j][rg] + bv;
                    const float x0 = (float)X0[(size_t)row * 512 + col];
                    outT[(size_t)row * 512 + col] = x0 + fmaxf(z, 0.f);
                }
            }
        }
    }
}

// ---------------------------------------------------------------------------
// Sinkhorn LSE passes over S = Q_ Q_^T / sqrt(512)  (S symmetric), log2-domain:
// ADD_U==0: out[i] = L2MU - log2(sum_m 2^(S[i][m]*s2))             (= u2)
// ADD_U==1: out[m] = L2MU - log2(sum_i 2^(S[m][i]*s2 + u2[i]))     (= v2)
// 128 rows/block, 4 waves x 32 rows (afr[2][2], acc[2][4]); grid (8,64)=512,
// XCD-swizzled. 8 B-reads feed 16 mfma per mt (was 8:8) -> LDS traffic per
// output halved. Qi A-frags mt-invariant, register-hoisted (proven R4 path).
// ---------------------------------------------------------------------------
template<int ADD_U>
__global__ __launch_bounds__(256, 4)
void sink_lse_kernel(const bf16* __restrict__ Qh, const float* __restrict__ uin,
                     float* __restrict__ out)
{
    __shared__ bf16 sQm[2][64 * LDT];       // 18432 B
    __shared__ float su[1024];              //  4096 B
    const int tid = threadIdx.x;
    const int lin = blockIdx.y * 8 + blockIdx.x;
    const int wk  = ((lin & 7) << 6) | (lin >> 3);
    const int bh = wk >> 3;
    const int rowTile = (wk & 7) * 128;
    const bf16* Qb = Qh + ((size_t)bh << 16);   // bh*1024*64

    if (ADD_U)
        *(float4*)(&su[tid * 4]) = *(const float4*)(uin + (bh << 10) + tid * 4);

    const int r0 = tid >> 3, kb0 = tid & 7;
    #pragma unroll
    for (int it = 0; it < 2; ++it)
        *(uint4*)(&sQm[0][(it * 32 + r0) * LDT + kb0 * 8]) =
            *(const uint4*)(Qb + ((it * 32 + r0) << 6) + kb0 * 8);

    const int w = tid >> 6, lane = tid & 63, quad = lane >> 4, l16 = lane & 15;
    // hoist Qi A-frags: rows rowTile + w*32 + a*16 + l16, a in {0,1}
    bf16x8 afr[2][2];
    #pragma unroll
    for (int a = 0; a < 2; ++a)
        #pragma unroll
        for (int kk = 0; kk < 2; ++kk)
            afr[a][kk] = *(const bf16x8*)(
                Qb + ((rowTile + w * 32 + a * 16 + l16) << 6) + kk * 32 + quad * 8);
    __syncthreads();

    float rsum[2][4] = {{0.f,0.f,0.f,0.f},{0.f,0.f,0.f,0.f}};

    for (int mt = 0; mt < 16; ++mt) {
        const int cur = mt & 1;
        uint4 pf[2];
        if (mt < 15) {
            #pragma unroll
            for (int it = 0; it < 2; ++it)
                pf[it] = *(const uint4*)(Qb + (((mt + 1) * 64 + it * 32 + r0) << 6) + kb0 * 8);
        }

        f32x4 acc[2][4];
        #pragma unroll
        for (int a = 0; a < 2; ++a)
            #pragma unroll
            for (int ct = 0; ct < 4; ++ct)
                #pragma unroll
                for (int e = 0; e < 4; ++e) acc[a][ct][e] = 0.f;

        #pragma unroll
        for (int kk = 0; kk < 2; ++kk) {
            bf16x8 bfr[4];
            #pragma unroll
            for (int ct = 0; ct < 4; ++ct)
                bfr[ct] = *(const bf16x8*)(&sQm[cur][(ct * 16 + l16) * LDT + kk * 32 + quad * 8]);
            #pragma unroll
            for (int a = 0; a < 2; ++a)
                #pragma unroll
                for (int ct = 0; ct < 4; ++ct)
                    acc[a][ct] = mfma16(afr[a][kk], bfr[ct], acc[a][ct]);
        }
        #pragma unroll
        for (int a = 0; a < 2; ++a)
            #pragma unroll
            for (int ct = 0; ct < 4; ++ct) {
                const float uadd = ADD_U ? su[mt * 64 + ct * 16 + l16] : 0.f;
                #pragma unroll
                for (int rg = 0; rg < 4; ++rg)
                    rsum[a][rg] += __builtin_amdgcn_exp2f(
                        fmaf(acc[a][ct][rg], SCALE2, uadd));
            }

        if (mt < 15) {
            #pragma unroll
            for (int it = 0; it < 2; ++it)
                *(uint4*)(&sQm[cur ^ 1][(it * 32 + r0) * LDT + kb0 * 8]) = pf[it];
        }
        __syncthreads();
    }
    #pragma unroll
    for (int off = 1; off < 16; off <<= 1)
        #pragma unroll
        for (int a = 0; a < 2; ++a)
            #pragma unroll
            for (int rg = 0; rg < 4; ++rg)
                rsum[a][rg] += __shfl_xor(rsum[a][rg], off);

    if (l16 == 0) {
        #pragma unroll
        for (int a = 0; a < 2; ++a)
            #pragma unroll
            for (int rg = 0; rg < 4; ++rg)
                out[(bh << 10) + rowTile + w * 32 + a * 16 + quad * 4 + rg] =
                    L2MU - __builtin_amdgcn_logf(rsum[a][rg]);
    }
}

// ---------------------------------------------------------------------------
// O_ = Q_ + A Q_,  A[i][m] = 2^(S[i][m]*s2 + u2[i] + v2[m] + 10).
// Swapped 32x32x16 QK^T; PV A-frags in-register (cvt_pk + permlane32_swap).
// 128 rows/block, 4 waves x 32 rows; grid (8, 64), XCD-swizzled.
// Round-9 harness-proven version: sQi PADDED, sv in LDS, bq hoisted,
// __launch_bounds__(256,2). NO-TOUCH: unpadded sQi / global-vf (R8+R10
// corrupt, absmax 8.016) and (256,3) cap (R7 corrupt).
// ---------------------------------------------------------------------------
template<int USE_T>
__global__ __launch_bounds__(256, 2)
void sink_av_kernel(const bf16* __restrict__ Qh, const bf16* __restrict__ QhT,
                    const float* __restrict__ u, const float* __restrict__ v,
                    float* __restrict__ O)
{
    __shared__ bf16 sQi[128 * LDT];         // 18432 B
    __shared__ bf16 sQm[2][64 * LDT];       // 18432 B
    __shared__ bf16 sQmT[2][64 * LDT];      // 18432 B  [dcol][m]
    __shared__ float sv[1024];              //  4096 B   -> total 59392 B
    const int tid = threadIdx.x;
    const int lin = blockIdx.y * 8 + blockIdx.x;
    const int wk  = ((lin & 7) << 6) | (lin >> 3);
    const int bh = wk >> 3;
    const int rowTile = (wk & 7) * 128;
    const bf16* Qb = Qh + ((size_t)bh << 16);
    const bf16* QbT = QhT + ((size_t)bh << 16);
    const int w = tid >> 6, lane = tid & 63, hi = lane >> 5, l31 = lane & 31;
    const int r0 = tid >> 3, kb0 = tid & 7;

    #pragma unroll
    for (int it = 0; it < 4; ++it) {
        int idx = it * 256 + tid;
        int r = idx >> 3, kb = idx & 7;
        *(uint4*)(&sQi[r * LDT + kb * 8]) =
            *(const uint4*)(Qb + ((rowTile + r) << 6) + kb * 8);
    }
    *(float4*)(&sv[tid * 4]) = *(const float4*)(v + (bh << 10) + tid * 4);
    const float u2p = u[(bh << 10) + rowTile + w * 32 + l31] + 10.f;

    #pragma unroll
    for (int it = 0; it < 2; ++it) {
        const int r = it * 32 + r0;
        uint4 val = *(const uint4*)(Qb + (r << 6) + kb0 * 8);
        *(uint4*)(&sQm[0][r * LDT + kb0 * 8]) = val;
        if (USE_T) {
            *(uint4*)(&sQmT[0][r * LDT + kb0 * 8]) =
                *(const uint4*)(QbT + (r << 10) + kb0 * 8);
        } else {
            union { uint4 q; bf16 e[8]; } cv; cv.q = val;
            #pragma unroll
            for (int j = 0; j < 8; ++j)
                sQmT[0][(kb0 * 8 + j) * LDT + r] = cv.e[j];
        }
    }
    __syncthreads();

    // hoist the mt-invariant Qi B-frags (row w*32 + l31) to registers
    bf16x8 bq[4];
    #pragma unroll
    for (int ks = 0; ks < 4; ++ks)
        bq[ks] = *(const bf16x8*)(&sQi[(w * 32 + l31) * LDT + ks * 16 + hi * 8]);

    f32x16 accO[2];
    #pragma unroll
    for (int dt = 0; dt < 2; ++dt)
        #pragma unroll
        for (int e = 0; e < 16; ++e) accO[dt][e] = 0.f;

    for (int mt = 0; mt < 16; ++mt) {
        const int cur = mt & 1;
        uint4 pfm[2], pft[2];
        if (mt < 15) {
            #pragma unroll
            for (int it = 0; it < 2; ++it) {
                const int r = it * 32 + r0;
                pfm[it] = *(const uint4*)(Qb + (((mt + 1) * 64 + r) << 6) + kb0 * 8);
                if (USE_T)
                    pft[it] = *(const uint4*)(QbT + (r << 10) + (mt + 1) * 64 + kb0 * 8);
            }
        }

        f32x16 accT[2];
        #pragma unroll
        for (int t = 0; t < 2; ++t)
            #pragma unroll
            for (int e = 0; e < 16; ++e) accT[t][e] = 0.f;
        #pragma unroll
        for (int ks = 0; ks < 4; ++ks) {
            #pragma unroll
            for (int t = 0; t < 2; ++t) {
                const bf16x8 am = *(const bf16x8*)(&sQm[cur][(t * 32 + l31) * LDT + ks * 16 + hi * 8]);
                accT[t] = mfma32(am, bq[ks], accT[t]);
            }
        }

        bf16x8 pa[4];
        #pragma unroll
        for (int t = 0; t < 2; ++t) {
            f32x4 vf[4];
            #pragma unroll
            for (int g = 0; g < 4; ++g)
                vf[g] = *(const f32x4*)(&sv[mt * 64 + t * 32 + g * 8 + hi * 4]);
            float p[16];
            #pragma unroll
            for (int r = 0; r < 16; ++r)
                p[r] = __builtin_amdgcn_exp2f(
                         fmaf(accT[t][r], SCALE2, u2p + vf[r >> 2][r & 3]));
            #pragma unroll
            for (int kk = 0; kk < 2; ++kk) {
                const int rb = kk * 8;
                unsigned X0 = cvtpk(p[rb + 0], p[rb + 1]);
                unsigned Y0 = cvtpk(p[rb + 4], p[rb + 5]);
                unsigned X1 = cvtpk(p[rb + 2], p[rb + 3]);
                unsigned Y1 = cvtpk(p[rb + 6], p[rb + 7]);
                uint32x2 s0 = __builtin_amdgcn_permlane32_swap(X0, Y0, false, false);
                uint32x2 s1 = __builtin_amdgcn_permlane32_swap(X1, Y1, false, false);
                union { unsigned wd[4]; bf16x8 v8; } u4;
                u4.wd[0] = s0[0]; u4.wd[1] = s1[0]; u4.wd[2] = s0[1]; u4.wd[3] = s1[1];
                pa[t * 2 + kk] = u4.v8;
            }
        }

        #pragma unroll
        for (int ks = 0; ks < 4; ++ks)
            #pragma unroll
            for (int dt = 0; dt < 2; ++dt) {
                const bf16x8 bt = *(const bf16x8*)(&sQmT[cur][(dt * 32 + l31) * LDT + ks * 16 + hi * 8]);
                accO[dt] = mfma32(pa[ks], bt, accO[dt]);
            }

        if (mt < 15) {
            #pragma unroll
            for (int it = 0; it < 2; ++it) {
                const int r = it * 32 + r0;
                *(uint4*)(&sQm[cur ^ 1][r * LDT + kb0 * 8]) = pfm[it];
                if (USE_T) {
                    *(uint4*)(&sQmT[cur ^ 1][r * LDT + kb0 * 8]) = pft[it];
                } else {
                    union { uint4 q; bf16 e[8]; } cv; cv.q = pfm[it];
                    #pragma unroll
                    for (int j = 0; j < 8; ++j)
                        sQmT[cur ^ 1][(kb0 * 8 + j) * LDT + r] = cv.e[j];
                }
            }
        }
        __syncthreads();
    }

    const int hh = bh >> 3, bb = bh & 7;
    #pragma unroll
    for (int dt = 0; dt < 2; ++dt) {
        const int dcol = dt * 32 + l31;
        #pragma unroll
        for (int r = 0; r < 16; ++r) {
            const int irow = w * 32 + (r & 3) + 8 * (r >> 2) + 4 * hi;
            const float o = (float)sQi[irow * LDT + dcol] + accO[dt][r];
            O[((size_t)(bb * 1024 + rowTile + irow) << 9) + (hh << 6) + dcol] = o;
        }
    }
}

// ---------------------------------------------------------------------------
// LayerNorm over 512 (eps 1e-5, biased var): ONE WAVE PER ROW, 4 rows/block.
// 8 elems/lane, pure shfl_xor reduce, no LDS/barrier. grid 2048 x 256.
// ---------------------------------------------------------------------------
template<typename OutT>
__global__ __launch_bounds__(256)
void ln_kernel(const float* __restrict__ X, const float* __restrict__ g,
               const float* __restrict__ bb, OutT* __restrict__ out)
{
    const int row = blockIdx.x * 4 + (threadIdx.x >> 6);
    const int lane = threadIdx.x & 63;
    const float* x = X + (size_t)row * 512 + lane * 8;
    const float4 a0 = *(const float4*)x;
    const float4 a1 = *(const float4*)(x + 4);
    float s  = a0.x + a0.y + a0.z + a0.w + a1.x + a1.y + a1.z + a1.w;
    float ss = a0.x*a0.x + a0.y*a0.y + a0.z*a0.z + a0.w*a0.w
             + a1.x*a1.x + a1.y*a1.y + a1.z*a1.z + a1.w*a1.w;
    #pragma unroll
    for (int off = 32; off; off >>= 1) {
        s  += __shfl_xor(s, off);
        ss += __shfl_xor(ss, off);
    }
    const float mean = s * (1.f / 512.f);
    const float rstd = rsqrtf(ss * (1.f / 512.f) - mean * mean + 1e-5f);
    const int c = lane * 8;
    const float4 g0 = *(const float4*)(g + c),  g1 = *(const float4*)(g + c + 4);
    const float4 b0 = *(const float4*)(bb + c), b1 = *(const float4*)(bb + c + 4);
    float y[8];
    y[0] = (a0.x - mean) * rstd * g0.x + b0.x;
    y[1] = (a0.y - mean) * rstd * g0.y + b0.y;
    y[2] = (a0.z - mean) * rstd * g0.z + b0.z;
    y[3] = (a0.w - mean) * rstd * g0.w + b0.w;
    y[4] = (a1.x - mean) * rstd * g1.x + b1.x;
    y[5] = (a1.y - mean) * rstd * g1.y + b1.y;
    y[6] = (a1.z - mean) * rstd * g1.z + b1.z;
    y[7] = (a1.w - mean) * rstd * g1.w + b1.w;
    if constexpr (sizeof(OutT) == 2) {
        bf16x8 h;
        #pragma unroll
        for (int j = 0; j < 8; ++j) h[j] = (bf16)y[j];
        *(bf16x8*)((bf16*)out + (size_t)row * 512 + c) = h;
    } else {
        float4 o0 = {y[0], y[1], y[2], y[3]};
        float4 o1 = {y[4], y[5], y[6], y[7]};
        *(float4*)((float*)out + (size_t)row * 512 + c)     = o0;
        *(float4*)((float*)out + (size_t)row * 512 + c + 4) = o1;
    }
}

// ---------------------------------------------------------------------------
extern "C" void kernel_launch(void* const* d_in, const int* in_sizes, int n_in,
                              void* d_out, int out_size, void* d_ws, size_t ws_size,
                              hipStream_t stream)
{
    const float* Q  = (const float*)d_in[0];
    // d_in[1] = K: accepted but unused by the reference
    const float* Wq = (const float*)d_in[2];
    const float* bq = (const float*)d_in[3];
    const float* Wo = (const float*)d_in[4];
    const float* bo = (const float*)d_in[5];
    const float* g0 = (const float*)d_in[6];
    const float* b0 = (const float*)d_in[7];
    const float* g1 = (const float*)d_in[8];
    const float* b1 = (const float*)d_in[9];

    char* ws = (char*)d_ws;
    const bool useT = ws_size >= (size_t)34078720;

    bf16 *Qh, *QhT, *X0, *Wqb, *Wob;
    float *u, *v, *Obuf;
    if (useT) {
        Qh   = (bf16*)ws;                        // [64][1024][64] bf16 : 8 MB
        QhT  = (bf16*)(ws + 8388608);            // [64][64][1024] bf16 : 8 MB
        X0   = (bf16*)(ws + 8388608);            // aliases QhT (dead after av)
        u    = (float*)(ws + 16777216);          // 256 KB
        v    = (float*)(ws + 17039360);          // 256 KB
        Obuf = (float*)(ws + 17301504);          // 16 MB (O, reused as T)
        Wqb  = (bf16*)(ws + 16777216);           // 512 KB, aliases u+v (dead until lse)
        Wob  = (bf16*)ws;                        // aliases Qh (dead after av)
    } else {
        Qh   = (bf16*)ws;
        QhT  = nullptr;
        X0   = (bf16*)ws;                        // aliases Qh
        u    = (float*)(ws + 8388608);
        v    = (float*)(ws + 8650752);
        Obuf = (float*)(ws + 8912896);
        Wqb  = (bf16*)(ws + 8388608);            // aliases u+v (dead until lse)
        Wob  = (bf16*)(ws + 8388608);            // aliases u+v (dead after av)
    }

    cvtw_kernel<<<128, 256, 0, stream>>>(Wq, Wqb);
    gemm_kernel<0><<<dim3(8, 64), 256, 0, stream>>>(Q, Wqb, bq, nullptr, Qh, QhT, nullptr);
    sink_lse_kernel<0><<<dim3(8, 64), 256, 0, stream>>>(Qh, nullptr, u);
    sink_lse_kernel<1><<<dim3(8, 64), 256, 0, stream>>>(Qh, u, v);
    if (useT)
        sink_av_kernel<1><<<dim3(8, 64), 256, 0, stream>>>(Qh, QhT, u, v, Obuf);
    else
        sink_av_kernel<0><<<dim3(8, 64), 256, 0, stream>>>(Qh, Qh, u, v, Obuf);
    cvtw_kernel<<<128, 256, 0, stream>>>(Wo, Wob);
    ln_kernel<bf16><<<2048, 256, 0, stream>>>(Obuf, g0, b0, X0);
    gemm_kernel<1><<<dim3(8, 64), 256, 0, stream>>>(X0, Wob, bo, X0, nullptr, nullptr, Obuf);
    ln_kernel<float><<<2048, 256, 0, stream>>>(Obuf, g1, b1, (float*)d_out);
}